// Round 5
// baseline (313.676 us; speedup 1.0000x reference)
//
#include <hip/hip_runtime.h>

#define HN 32
#define MM 16
#define DD 128
#define NN 4096
#define PP 8192
#define TP 32
#define NCH 48
#define CLEN 171                 // 48*171 = 8208 = PP+MM exactly
#define NTILE 6                  // ceil(171/32), last tile valid=11

// ---------------- Kernel 1: QKV projection (atomic accumulate) ----------------
// grid = 768 : mat(3) x coltile(8 x 512) x rowchunk(32 x 128); 16 loads in flight
__global__ __launch_bounds__(256) void qkv_kernel(
    const float* __restrict__ X, const float* __restrict__ Wq,
    const float* __restrict__ Wk, const float* __restrict__ Wv,
    float* __restrict__ qkv)
{
    __shared__ float Xs[MM][128];
    const int bx  = blockIdx.x;
    const int mat = bx >> 8;
    const int r   = bx & 255;
    const int ct  = r >> 5;           // 0..7
    const int rc  = r & 31;           // 0..31
    const int col0 = ct << 9;
    const int i0   = rc << 7;
    const float* W = (mat == 0) ? Wq : (mat == 1) ? Wk : Wv;
    const int t = threadIdx.x;

    for (int f = t; f < MM*128; f += 256)
        Xs[f >> 7][f & 127] = X[(f >> 7)*NN + i0 + (f & 127)];
    __syncthreads();

    const int c0 = col0 + t, c1 = col0 + 256 + t;
    float a0[MM], a1[MM];
#pragma unroll
    for (int m = 0; m < MM; ++m) { a0[m] = 0.f; a1[m] = 0.f; }

    for (int i8 = 0; i8 < 128; i8 += 8) {
        const float* Wr = W + (size_t)(i0 + i8) * NN;
        float w0[8], w1[8];
#pragma unroll
        for (int rr = 0; rr < 8; ++rr) {        // 16 loads in flight
            w0[rr] = Wr[(size_t)rr*NN + c0];
            w1[rr] = Wr[(size_t)rr*NN + c1];
        }
#pragma unroll
        for (int m = 0; m < MM; ++m) {
            float4 xa = *reinterpret_cast<const float4*>(&Xs[m][i8]);
            float4 xb = *reinterpret_cast<const float4*>(&Xs[m][i8 + 4]);
            a0[m] += xa.x*w0[0] + xa.y*w0[1] + xa.z*w0[2] + xa.w*w0[3]
                   + xb.x*w0[4] + xb.y*w0[5] + xb.z*w0[6] + xb.w*w0[7];
            a1[m] += xa.x*w1[0] + xa.y*w1[1] + xa.z*w1[2] + xa.w*w1[3]
                   + xb.x*w1[4] + xb.y*w1[5] + xb.z*w1[6] + xb.w*w1[7];
        }
    }
    float* base = qkv + (size_t)mat * HN*MM*DD;
    const int h0 = c0 >> 7, d0 = c0 & 127;
    const int h1 = c1 >> 7, d1 = c1 & 127;
#pragma unroll
    for (int m = 0; m < MM; ++m) {
        atomicAdd(&base[(h0*MM + m)*DD + d0], a0[m]);
        atomicAdd(&base[(h1*MM + m)*DD + d1], a1[m]);
    }
}

// ---------------- Kernel 2: flash-decode partials, 32-row tiles, high occupancy ----------------
// grid = (NCH=48, HN=32) = 1536 blocks = exactly 6/CU at launch_bounds(256,6).
// 4 waves; wave wv owns m rows 4wv..4wv+3; lane-halves split the m-pairs in scores.
__global__ __launch_bounds__(256, 6) void attn_partial5(
    const float* __restrict__ cacheK, const float* __restrict__ cacheV,
    const float* __restrict__ qkv, float* __restrict__ pmu,
    float* __restrict__ ps, float* __restrict__ pacc)
{
    __shared__ float KV[TP][DD + 4];   // 16.9 KB
    __shared__ float Wl[TP][20];       // 2.56 KB ; &Wl[p][4w] stays 16B-aligned (80p%16==0)

    const int chunk = blockIdx.x;
    const int h     = blockIdx.y;
    const int t     = threadIdx.x;
    const int lane  = t & 63;
    const int wv    = __builtin_amdgcn_readfirstlane((int)(threadIdx.x >> 6));
    const int hf    = lane >> 5;       // lane half: m-pair select
    const int p     = lane & 31;       // score KV row
    const int srow  = t >> 3;          // staging row 0..31
    const int sg    = t & 7;           // staging granule base
    const int psi   = lane >> 4;       // PV p-phase 0..3
    const int g     = lane & 15;       // PV d-slice (8 floats)

    const float* k_ws = qkv + HN*MM*DD;
    const float* v_ws = qkv + 2*HN*MM*DD;
    const int start = chunk * CLEN;
    // per-lane-half Q rows (L1-resident vector loads)
    const float* qA = qkv + ((size_t)h*MM + 4*wv + 2*hf)*DD;
    const float* qB = qA + DD;

    float mu0 = -3.0e38f, mu1 = -3.0e38f, mu2 = -3.0e38f, mu3 = -3.0e38f;
    float ss0 = 0.f, ss1 = 0.f, ss2 = 0.f, ss3 = 0.f;
    float acc[4][8];
#pragma unroll
    for (int q = 0; q < 4; ++q)
#pragma unroll
        for (int k = 0; k < 8; ++k) acc[q][k] = 0.f;

    for (int tt = 0; tt < NTILE; ++tt) {
        const int valid = min(TP, CLEN - tt*TP);
        const int vr    = min(start + tt*TP + srow, PP + MM - 1);  // clamp: garbage rows masked
        const float* srcK = (vr < PP) ? cacheK + ((size_t)h*PP + vr)*DD
                                      : k_ws + ((size_t)h*MM + (vr - PP))*DD;
        const float* srcV = (vr < PP) ? cacheV + ((size_t)h*PP + vr)*DD
                                      : v_ws + ((size_t)h*MM + (vr - PP))*DD;

        __syncthreads();                  // B0: PV(tt-1) done reading KV
        {   // stage K: 4 float4 per thread, load->write immediately (no held state)
            float4 k0 = *reinterpret_cast<const float4*>(srcK + 4*sg);
            float4 k1 = *reinterpret_cast<const float4*>(srcK + 4*sg + 32);
            float4 k2 = *reinterpret_cast<const float4*>(srcK + 4*sg + 64);
            float4 k3 = *reinterpret_cast<const float4*>(srcK + 4*sg + 96);
            *reinterpret_cast<float4*>(&KV[srow][4*sg])      = k0;
            *reinterpret_cast<float4*>(&KV[srow][4*sg + 32]) = k1;
            *reinterpret_cast<float4*>(&KV[srow][4*sg + 64]) = k2;
            *reinterpret_cast<float4*>(&KV[srow][4*sg + 96]) = k3;
        }
        __syncthreads();                  // B1: K visible

        // ---- scores: lane-half owns 2 m-rows over 32 p ----
        float sA = 0.f, sB = 0.f;
#pragma unroll 8
        for (int dq = 0; dq < 32; ++dq) {
            float4 k = *reinterpret_cast<const float4*>(&KV[p][dq*4]);
            float4 a = *reinterpret_cast<const float4*>(qA + dq*4);
            float4 b = *reinterpret_cast<const float4*>(qB + dq*4);
            sA += k.x*a.x + k.y*a.y + k.z*a.z + k.w*a.w;
            sB += k.x*b.x + k.y*b.y + k.z*b.z + k.w*b.w;
        }
        if (p >= valid) { sA = -3.0e38f; sB = -3.0e38f; }

        __syncthreads();                  // B2: K reads done; KV free for V
        {   // stage V
            float4 v0 = *reinterpret_cast<const float4*>(srcV + 4*sg);
            float4 v1 = *reinterpret_cast<const float4*>(srcV + 4*sg + 32);
            float4 v2 = *reinterpret_cast<const float4*>(srcV + 4*sg + 64);
            float4 v3 = *reinterpret_cast<const float4*>(srcV + 4*sg + 96);
            *reinterpret_cast<float4*>(&KV[srow][4*sg])      = v0;
            *reinterpret_cast<float4*>(&KV[srow][4*sg + 32]) = v1;
            *reinterpret_cast<float4*>(&KV[srow][4*sg + 64]) = v2;
            *reinterpret_cast<float4*>(&KV[srow][4*sg + 96]) = v3;
        }

        // ---- softmax: within-half reduce (32 lanes) + one cross-half exchange ----
        float mA = sA, mB = sB;
#pragma unroll
        for (int off = 1; off < 32; off <<= 1) {
            mA = fmaxf(mA, __shfl_xor(mA, off));
            mB = fmaxf(mB, __shfl_xor(mB, off));
        }
        const float mAo = __shfl_xor(mA, 32), mBo = __shfl_xor(mB, 32);
        const float m0 = hf ? mAo : mA, m1 = hf ? mBo : mB;
        const float m2 = hf ? mA : mAo, m3 = hf ? mB : mBo;
        const float n0 = fmaxf(mu0, m0), n1 = fmaxf(mu1, m1);
        const float n2 = fmaxf(mu2, m2), n3 = fmaxf(mu3, m3);
        const float r0 = __expf(mu0 - n0), r1 = __expf(mu1 - n1);
        const float r2 = __expf(mu2 - n2), r3 = __expf(mu3 - n3);
        const float wA = __expf(sA - (hf ? n2 : n0));   // invalid p -> exp(-inf)=0
        const float wB = __expf(sB - (hf ? n3 : n1));
        float tA = wA, tB = wB;
#pragma unroll
        for (int off = 1; off < 32; off <<= 1) {
            tA += __shfl_xor(tA, off);
            tB += __shfl_xor(tB, off);
        }
        const float tAo = __shfl_xor(tA, 32), tBo = __shfl_xor(tB, 32);
        ss0 = ss0*r0 + (hf ? tAo : tA);
        ss1 = ss1*r1 + (hf ? tBo : tB);
        ss2 = ss2*r2 + (hf ? tA : tAo);
        ss3 = ss3*r3 + (hf ? tB : tBo);
        mu0 = n0; mu1 = n1; mu2 = n2; mu3 = n3;
        *reinterpret_cast<float2*>(&Wl[p][4*wv + 2*hf]) = make_float2(wA, wB);

        __syncthreads();                  // B3: V + Wl visible

        // ---- PV accumulate: lane (psi,g); p = psi + 4i ----
#pragma unroll
        for (int k = 0; k < 8; ++k) {
            acc[0][k] *= r0; acc[1][k] *= r1; acc[2][k] *= r2; acc[3][k] *= r3;
        }
#pragma unroll
        for (int i = 0; i < 8; ++i) {
            const int pp = psi + 4*i;
            float4 wq = *reinterpret_cast<const float4*>(&Wl[pp][4*wv]);
            float4 v0 = *reinterpret_cast<const float4*>(&KV[pp][g*8]);
            float4 v1 = *reinterpret_cast<const float4*>(&KV[pp][g*8 + 4]);
            acc[0][0] += wq.x*v0.x; acc[0][1] += wq.x*v0.y; acc[0][2] += wq.x*v0.z; acc[0][3] += wq.x*v0.w;
            acc[0][4] += wq.x*v1.x; acc[0][5] += wq.x*v1.y; acc[0][6] += wq.x*v1.z; acc[0][7] += wq.x*v1.w;
            acc[1][0] += wq.y*v0.x; acc[1][1] += wq.y*v0.y; acc[1][2] += wq.y*v0.z; acc[1][3] += wq.y*v0.w;
            acc[1][4] += wq.y*v1.x; acc[1][5] += wq.y*v1.y; acc[1][6] += wq.y*v1.z; acc[1][7] += wq.y*v1.w;
            acc[2][0] += wq.z*v0.x; acc[2][1] += wq.z*v0.y; acc[2][2] += wq.z*v0.z; acc[2][3] += wq.z*v0.w;
            acc[2][4] += wq.z*v1.x; acc[2][5] += wq.z*v1.y; acc[2][6] += wq.z*v1.z; acc[2][7] += wq.z*v1.w;
            acc[3][0] += wq.w*v0.x; acc[3][1] += wq.w*v0.y; acc[3][2] += wq.w*v0.z; acc[3][3] += wq.w*v0.w;
            acc[3][4] += wq.w*v1.x; acc[3][5] += wq.w*v1.y; acc[3][6] += wq.w*v1.z; acc[3][7] += wq.w*v1.w;
        }
    }

    // ---- epilogue: reduce psi-partials via shuffles, write partials ----
#pragma unroll
    for (int q = 0; q < 4; ++q)
#pragma unroll
        for (int k = 0; k < 8; ++k) {
            float v = acc[q][k];
            v += __shfl_xor(v, 16);
            v += __shfl_xor(v, 32);
            acc[q][k] = v;
        }
    if (psi == 0 && lane < 16) {
        float* pa = pacc + ((size_t)(h*NCH + chunk)*MM + 4*wv)*DD;
#pragma unroll
        for (int q = 0; q < 4; ++q) {
            *reinterpret_cast<float4*>(pa + q*DD + g*8) =
                make_float4(acc[q][0], acc[q][1], acc[q][2], acc[q][3]);
            *reinterpret_cast<float4*>(pa + q*DD + g*8 + 4) =
                make_float4(acc[q][4], acc[q][5], acc[q][6], acc[q][7]);
        }
    }
    if (lane == 0) {
        const int o = (h*NCH + chunk)*MM + 4*wv;
        pmu[o + 0] = mu0; pmu[o + 1] = mu1; pmu[o + 2] = mu2; pmu[o + 3] = mu3;
        ps [o + 0] = ss0; ps [o + 1] = ss1; ps [o + 2] = ss2; ps [o + 3] = ss3;
    }
}

// ---------------- Kernel 3: combine partials ----------------
__global__ __launch_bounds__(128) void combine_kernel(
    const float* __restrict__ pmu, const float* __restrict__ ps,
    const float* __restrict__ pacc, float* __restrict__ out)
{
    const int b = blockIdx.x;          // h*16 + m
    const int h = b >> 4, m = b & 15;
    const int d = threadIdx.x;
    float gm = -3.0e38f;
#pragma unroll 8
    for (int c = 0; c < NCH; ++c)
        gm = fmaxf(gm, pmu[(h*NCH + c)*MM + m]);
    float stot = 0.f, a = 0.f;
#pragma unroll 8
    for (int c = 0; c < NCH; ++c) {
        const float f = __expf(pmu[(h*NCH + c)*MM + m] - gm);
        stot += ps[(h*NCH + c)*MM + m] * f;
        a += pacc[((size_t)(h*NCH + c)*MM + m)*DD + d] * f;
    }
    out[m*NN + h*DD + d] = a / stot;
}

extern "C" void kernel_launch(void* const* d_in, const int* in_sizes, int n_in,
                              void* d_out, int out_size, void* d_ws, size_t ws_size,
                              hipStream_t stream) {
    const float* X  = (const float*)d_in[0];
    const float* Wq = (const float*)d_in[1];
    const float* Wk = (const float*)d_in[2];
    const float* Wv = (const float*)d_in[3];
    const float* cK = (const float*)d_in[4];
    const float* cV = (const float*)d_in[5];
    float* out = (float*)d_out;

    float* ws     = (float*)d_ws;
    float* qkv    = ws;
    float* pmu_p  = ws + 3*HN*MM*DD;
    float* ps_p   = pmu_p + HN*NCH*MM;
    float* pacc_p = ps_p + HN*NCH*MM;

    hipMemsetAsync(qkv, 0, (size_t)3*HN*MM*DD*sizeof(float), stream);
    qkv_kernel<<<768, 256, 0, stream>>>(X, Wq, Wk, Wv, qkv);
    attn_partial5<<<dim3(NCH, HN), 256, 0, stream>>>(cK, cV, qkv, pmu_p, ps_p, pacc_p);
    combine_kernel<<<HN*MM, 128, 0, stream>>>(pmu_p, ps_p, pacc_p, out);
}

// Round 6
// 206.517 us; speedup vs baseline: 1.5189x; 1.5189x over previous
//
#include <hip/hip_runtime.h>

#define HN 32
#define MM 16
#define DD 128
#define NN 4096
#define PP 8192
#define TP 32
#define NCH 48
#define CLEN 171                 // 48*171 = 8208 = PP+MM exactly
#define NTILE 6                  // ceil(171/32), last tile valid=11

// ---------------- Kernel 1: QKV projection (atomic accumulate) ----------------
// grid = 768 : mat(3) x coltile(8 x 512) x rowchunk(32 x 128); 32 loads in flight
__global__ __launch_bounds__(256) void qkv_kernel(
    const float* __restrict__ X, const float* __restrict__ Wq,
    const float* __restrict__ Wk, const float* __restrict__ Wv,
    float* __restrict__ qkv)
{
    __shared__ float Xs[MM][128];
    const int bx  = blockIdx.x;
    const int mat = bx >> 8;
    const int r   = bx & 255;
    const int ct  = r >> 5;           // 0..7
    const int rc  = r & 31;           // 0..31
    const int col0 = ct << 9;
    const int i0   = rc << 7;
    const float* W = (mat == 0) ? Wq : (mat == 1) ? Wk : Wv;
    const int t = threadIdx.x;

    for (int f = t; f < MM*128; f += 256)
        Xs[f >> 7][f & 127] = X[(f >> 7)*NN + i0 + (f & 127)];
    __syncthreads();

    const int c0 = col0 + t, c1 = col0 + 256 + t;
    float a0[MM], a1[MM];
#pragma unroll
    for (int m = 0; m < MM; ++m) { a0[m] = 0.f; a1[m] = 0.f; }

    for (int i16 = 0; i16 < 128; i16 += 16) {
        const float* Wr = W + (size_t)(i0 + i16) * NN;
        float w0[16], w1[16];
#pragma unroll
        for (int rr = 0; rr < 16; ++rr) {       // 32 loads in flight
            w0[rr] = Wr[(size_t)rr*NN + c0];
            w1[rr] = Wr[(size_t)rr*NN + c1];
        }
#pragma unroll
        for (int m = 0; m < MM; ++m) {
            float4 xa = *reinterpret_cast<const float4*>(&Xs[m][i16]);
            float4 xb = *reinterpret_cast<const float4*>(&Xs[m][i16 + 4]);
            float4 xc = *reinterpret_cast<const float4*>(&Xs[m][i16 + 8]);
            float4 xd = *reinterpret_cast<const float4*>(&Xs[m][i16 + 12]);
            a0[m] += xa.x*w0[0] + xa.y*w0[1] + xa.z*w0[2] + xa.w*w0[3]
                   + xb.x*w0[4] + xb.y*w0[5] + xb.z*w0[6] + xb.w*w0[7]
                   + xc.x*w0[8] + xc.y*w0[9] + xc.z*w0[10] + xc.w*w0[11]
                   + xd.x*w0[12] + xd.y*w0[13] + xd.z*w0[14] + xd.w*w0[15];
            a1[m] += xa.x*w1[0] + xa.y*w1[1] + xa.z*w1[2] + xa.w*w1[3]
                   + xb.x*w1[4] + xb.y*w1[5] + xb.z*w1[6] + xb.w*w1[7]
                   + xc.x*w1[8] + xc.y*w1[9] + xc.z*w1[10] + xc.w*w1[11]
                   + xd.x*w1[12] + xd.y*w1[13] + xd.z*w1[14] + xd.w*w1[15];
        }
    }
    float* base = qkv + (size_t)mat * HN*MM*DD;
    const int h0 = c0 >> 7, d0 = c0 & 127;
    const int h1 = c1 >> 7, d1 = c1 & 127;
#pragma unroll
    for (int m = 0; m < MM; ++m) {
        atomicAdd(&base[(h0*MM + m)*DD + d0], a0[m]);
        atomicAdd(&base[(h1*MM + m)*DD + d1], a1[m]);
    }
}

// ---------------- Kernel 2: flash-decode partials, 32-row tiles ----------------
// grid = (NCH=48, HN=32) = 1536 blocks. launch_bounds(256,2): VGPR cap 128 (no spill);
// occupancy self-limits via ~80 VGPR + 19.5KB LDS -> ~6 blocks/CU resident.
__global__ __launch_bounds__(256, 2) void attn_partial5(
    const float* __restrict__ cacheK, const float* __restrict__ cacheV,
    const float* __restrict__ qkv, float* __restrict__ pmu,
    float* __restrict__ ps, float* __restrict__ pacc)
{
    __shared__ float KV[TP][DD + 4];   // 16.9 KB
    __shared__ float Wl[TP][20];       // 2.56 KB ; &Wl[p][4w] stays 16B-aligned

    const int chunk = blockIdx.x;
    const int h     = blockIdx.y;
    const int t     = threadIdx.x;
    const int lane  = t & 63;
    const int wv    = __builtin_amdgcn_readfirstlane((int)(threadIdx.x >> 6));
    const int hf    = lane >> 5;       // lane half: m-pair select
    const int p     = lane & 31;       // score KV row
    const int srow  = t >> 3;          // staging row 0..31
    const int sg    = t & 7;           // staging granule base
    const int psi   = lane >> 4;       // PV p-phase 0..3
    const int g     = lane & 15;       // PV d-slice (8 floats)

    const float* k_ws = qkv + HN*MM*DD;
    const float* v_ws = qkv + 2*HN*MM*DD;
    const int start = chunk * CLEN;
    // per-lane-half Q rows (L1-resident vector loads)
    const float* qA = qkv + ((size_t)h*MM + 4*wv + 2*hf)*DD;
    const float* qB = qA + DD;

    float mu0 = -3.0e38f, mu1 = -3.0e38f, mu2 = -3.0e38f, mu3 = -3.0e38f;
    float ss0 = 0.f, ss1 = 0.f, ss2 = 0.f, ss3 = 0.f;
    float acc[4][8];
#pragma unroll
    for (int q = 0; q < 4; ++q)
#pragma unroll
        for (int k = 0; k < 8; ++k) acc[q][k] = 0.f;

    for (int tt = 0; tt < NTILE; ++tt) {
        const int valid = min(TP, CLEN - tt*TP);
        const int vr    = min(start + tt*TP + srow, PP + MM - 1);  // clamp: garbage rows masked
        const float* srcK = (vr < PP) ? cacheK + ((size_t)h*PP + vr)*DD
                                      : k_ws + ((size_t)h*MM + (vr - PP))*DD;
        const float* srcV = (vr < PP) ? cacheV + ((size_t)h*PP + vr)*DD
                                      : v_ws + ((size_t)h*MM + (vr - PP))*DD;

        __syncthreads();                  // B0: PV(tt-1) done reading KV
        {   // stage K: 4 float4 per thread, load->write immediately (no held state)
            float4 k0 = *reinterpret_cast<const float4*>(srcK + 4*sg);
            float4 k1 = *reinterpret_cast<const float4*>(srcK + 4*sg + 32);
            float4 k2 = *reinterpret_cast<const float4*>(srcK + 4*sg + 64);
            float4 k3 = *reinterpret_cast<const float4*>(srcK + 4*sg + 96);
            *reinterpret_cast<float4*>(&KV[srow][4*sg])      = k0;
            *reinterpret_cast<float4*>(&KV[srow][4*sg + 32]) = k1;
            *reinterpret_cast<float4*>(&KV[srow][4*sg + 64]) = k2;
            *reinterpret_cast<float4*>(&KV[srow][4*sg + 96]) = k3;
        }
        __syncthreads();                  // B1: K visible

        // ---- scores: lane-half owns 2 m-rows over 32 p ----
        float sA = 0.f, sB = 0.f;
#pragma unroll 8
        for (int dq = 0; dq < 32; ++dq) {
            float4 k = *reinterpret_cast<const float4*>(&KV[p][dq*4]);
            float4 a = *reinterpret_cast<const float4*>(qA + dq*4);
            float4 b = *reinterpret_cast<const float4*>(qB + dq*4);
            sA += k.x*a.x + k.y*a.y + k.z*a.z + k.w*a.w;
            sB += k.x*b.x + k.y*b.y + k.z*b.z + k.w*b.w;
        }
        if (p >= valid) { sA = -3.0e38f; sB = -3.0e38f; }

        __syncthreads();                  // B2: K reads done; KV free for V
        {   // stage V
            float4 v0 = *reinterpret_cast<const float4*>(srcV + 4*sg);
            float4 v1 = *reinterpret_cast<const float4*>(srcV + 4*sg + 32);
            float4 v2 = *reinterpret_cast<const float4*>(srcV + 4*sg + 64);
            float4 v3 = *reinterpret_cast<const float4*>(srcV + 4*sg + 96);
            *reinterpret_cast<float4*>(&KV[srow][4*sg])      = v0;
            *reinterpret_cast<float4*>(&KV[srow][4*sg + 32]) = v1;
            *reinterpret_cast<float4*>(&KV[srow][4*sg + 64]) = v2;
            *reinterpret_cast<float4*>(&KV[srow][4*sg + 96]) = v3;
        }

        // ---- softmax: within-half reduce (32 lanes) + one cross-half exchange ----
        float mA = sA, mB = sB;
#pragma unroll
        for (int off = 1; off < 32; off <<= 1) {
            mA = fmaxf(mA, __shfl_xor(mA, off));
            mB = fmaxf(mB, __shfl_xor(mB, off));
        }
        const float mAo = __shfl_xor(mA, 32), mBo = __shfl_xor(mB, 32);
        const float m0 = hf ? mAo : mA, m1 = hf ? mBo : mB;
        const float m2 = hf ? mA : mAo, m3 = hf ? mB : mBo;
        const float n0 = fmaxf(mu0, m0), n1 = fmaxf(mu1, m1);
        const float n2 = fmaxf(mu2, m2), n3 = fmaxf(mu3, m3);
        const float r0 = __expf(mu0 - n0), r1 = __expf(mu1 - n1);
        const float r2 = __expf(mu2 - n2), r3 = __expf(mu3 - n3);
        const float wA = __expf(sA - (hf ? n2 : n0));   // invalid p -> exp(-inf)=0
        const float wB = __expf(sB - (hf ? n3 : n1));
        float tA = wA, tB = wB;
#pragma unroll
        for (int off = 1; off < 32; off <<= 1) {
            tA += __shfl_xor(tA, off);
            tB += __shfl_xor(tB, off);
        }
        const float tAo = __shfl_xor(tA, 32), tBo = __shfl_xor(tB, 32);
        ss0 = ss0*r0 + (hf ? tAo : tA);
        ss1 = ss1*r1 + (hf ? tBo : tB);
        ss2 = ss2*r2 + (hf ? tA : tAo);
        ss3 = ss3*r3 + (hf ? tB : tBo);
        mu0 = n0; mu1 = n1; mu2 = n2; mu3 = n3;
        *reinterpret_cast<float2*>(&Wl[p][4*wv + 2*hf]) = make_float2(wA, wB);

        __syncthreads();                  // B3: V + Wl visible

        // ---- PV accumulate: lane (psi,g); p = psi + 4i ----
#pragma unroll
        for (int k = 0; k < 8; ++k) {
            acc[0][k] *= r0; acc[1][k] *= r1; acc[2][k] *= r2; acc[3][k] *= r3;
        }
#pragma unroll
        for (int i = 0; i < 8; ++i) {
            const int pp = psi + 4*i;
            float4 wq = *reinterpret_cast<const float4*>(&Wl[pp][4*wv]);
            float4 v0 = *reinterpret_cast<const float4*>(&KV[pp][g*8]);
            float4 v1 = *reinterpret_cast<const float4*>(&KV[pp][g*8 + 4]);
            acc[0][0] += wq.x*v0.x; acc[0][1] += wq.x*v0.y; acc[0][2] += wq.x*v0.z; acc[0][3] += wq.x*v0.w;
            acc[0][4] += wq.x*v1.x; acc[0][5] += wq.x*v1.y; acc[0][6] += wq.x*v1.z; acc[0][7] += wq.x*v1.w;
            acc[1][0] += wq.y*v0.x; acc[1][1] += wq.y*v0.y; acc[1][2] += wq.y*v0.z; acc[1][3] += wq.y*v0.w;
            acc[1][4] += wq.y*v1.x; acc[1][5] += wq.y*v1.y; acc[1][6] += wq.y*v1.z; acc[1][7] += wq.y*v1.w;
            acc[2][0] += wq.z*v0.x; acc[2][1] += wq.z*v0.y; acc[2][2] += wq.z*v0.z; acc[2][3] += wq.z*v0.w;
            acc[2][4] += wq.z*v1.x; acc[2][5] += wq.z*v1.y; acc[2][6] += wq.z*v1.z; acc[2][7] += wq.z*v1.w;
            acc[3][0] += wq.w*v0.x; acc[3][1] += wq.w*v0.y; acc[3][2] += wq.w*v0.z; acc[3][3] += wq.w*v0.w;
            acc[3][4] += wq.w*v1.x; acc[3][5] += wq.w*v1.y; acc[3][6] += wq.w*v1.z; acc[3][7] += wq.w*v1.w;
        }
    }

    // ---- epilogue: reduce psi-partials via shuffles, write partials ----
#pragma unroll
    for (int q = 0; q < 4; ++q)
#pragma unroll
        for (int k = 0; k < 8; ++k) {
            float v = acc[q][k];
            v += __shfl_xor(v, 16);
            v += __shfl_xor(v, 32);
            acc[q][k] = v;
        }
    if (lane < 16) {
        float* pa = pacc + ((size_t)(h*NCH + chunk)*MM + 4*wv)*DD;
#pragma unroll
        for (int q = 0; q < 4; ++q) {
            *reinterpret_cast<float4*>(pa + q*DD + g*8) =
                make_float4(acc[q][0], acc[q][1], acc[q][2], acc[q][3]);
            *reinterpret_cast<float4*>(pa + q*DD + g*8 + 4) =
                make_float4(acc[q][4], acc[q][5], acc[q][6], acc[q][7]);
        }
    }
    if (lane == 0) {
        const int o = (h*NCH + chunk)*MM + 4*wv;
        pmu[o + 0] = mu0; pmu[o + 1] = mu1; pmu[o + 2] = mu2; pmu[o + 3] = mu3;
        ps [o + 0] = ss0; ps [o + 1] = ss1; ps [o + 2] = ss2; ss3 = ss3;
        ps [o + 3] = ss3; ps [o + 2] = ss2;
    }
}

// ---------------- Kernel 3: combine partials ----------------
__global__ __launch_bounds__(128) void combine_kernel(
    const float* __restrict__ pmu, const float* __restrict__ ps,
    const float* __restrict__ pacc, float* __restrict__ out)
{
    const int b = blockIdx.x;          // h*16 + m
    const int h = b >> 4, m = b & 15;
    const int d = threadIdx.x;
    float gm = -3.0e38f;
#pragma unroll 8
    for (int c = 0; c < NCH; ++c)
        gm = fmaxf(gm, pmu[(h*NCH + c)*MM + m]);
    float stot = 0.f, a = 0.f;
#pragma unroll 8
    for (int c = 0; c < NCH; ++c) {
        const float f = __expf(pmu[(h*NCH + c)*MM + m] - gm);
        stot += ps[(h*NCH + c)*MM + m] * f;
        a += pacc[((size_t)(h*NCH + c)*MM + m)*DD + d] * f;
    }
    out[m*NN + h*DD + d] = a / stot;
}

extern "C" void kernel_launch(void* const* d_in, const int* in_sizes, int n_in,
                              void* d_out, int out_size, void* d_ws, size_t ws_size,
                              hipStream_t stream) {
    const float* X  = (const float*)d_in[0];
    const float* Wq = (const float*)d_in[1];
    const float* Wk = (const float*)d_in[2];
    const float* Wv = (const float*)d_in[3];
    const float* cK = (const float*)d_in[4];
    const float* cV = (const float*)d_in[5];
    float* out = (float*)d_out;

    float* ws     = (float*)d_ws;
    float* qkv    = ws;
    float* pmu_p  = ws + 3*HN*MM*DD;
    float* ps_p   = pmu_p + HN*NCH*MM;
    float* pacc_p = ps_p + HN*NCH*MM;

    hipMemsetAsync(qkv, 0, (size_t)3*HN*MM*DD*sizeof(float), stream);
    qkv_kernel<<<768, 256, 0, stream>>>(X, Wq, Wk, Wv, qkv);
    attn_partial5<<<dim3(NCH, HN), 256, 0, stream>>>(cK, cV, qkv, pmu_p, ps_p, pacc_p);
    combine_kernel<<<HN*MM, 128, 0, stream>>>(pmu_p, ps_p, pacc_p, out);
}

// Round 7
// 177.566 us; speedup vs baseline: 1.7665x; 1.1630x over previous
//
#include <hip/hip_runtime.h>

#define HN 32
#define MM 16
#define DD 128
#define NN 4096
#define PP 8192
#define TP 64
#define NCH 32
#define CROWS 256              // cache rows per chunk; 32*256 = 8192

// ---------------- Kernel 1: QKV projection (atomic accumulate) ----------------
// grid = 768 : mat(3) x coltile(8 x 512) x rowchunk(32 x 128).
// X read via block-uniform float4 loads -> scalar cache (no LDS at all).
__global__ __launch_bounds__(256) void qkv_kernel(
    const float* __restrict__ X, const float* __restrict__ Wq,
    const float* __restrict__ Wk, const float* __restrict__ Wv,
    float* __restrict__ qkv)
{
    const int bx  = blockIdx.x;
    const int mat = bx >> 8;
    const int r   = bx & 255;
    const int ct  = r >> 5;           // 0..7
    const int rc  = r & 31;           // 0..31
    const int col0 = ct << 9;
    const int i0   = rc << 7;
    const float* W = (mat == 0) ? Wq : (mat == 1) ? Wk : Wv;
    const int t = threadIdx.x;

    const int c0 = col0 + t, c1 = col0 + 256 + t;
    float a0[MM], a1[MM];
#pragma unroll
    for (int m = 0; m < MM; ++m) { a0[m] = 0.f; a1[m] = 0.f; }

    for (int i8 = 0; i8 < 128; i8 += 8) {
        const float* Wr = W + (size_t)(i0 + i8) * NN;
        float w0[8], w1[8];
#pragma unroll
        for (int rr = 0; rr < 8; ++rr) {        // 16 vector loads in flight
            w0[rr] = Wr[(size_t)rr*NN + c0];
            w1[rr] = Wr[(size_t)rr*NN + c1];
        }
        const float* Xr = X + i0 + i8;          // block-uniform base
#pragma unroll
        for (int m = 0; m < MM; ++m) {
            float4 xa = *reinterpret_cast<const float4*>(Xr + (size_t)m*NN);
            float4 xb = *reinterpret_cast<const float4*>(Xr + (size_t)m*NN + 4);
            a0[m] += xa.x*w0[0] + xa.y*w0[1] + xa.z*w0[2] + xa.w*w0[3]
                   + xb.x*w0[4] + xb.y*w0[5] + xb.z*w0[6] + xb.w*w0[7];
            a1[m] += xa.x*w1[0] + xa.y*w1[1] + xa.z*w1[2] + xa.w*w1[3]
                   + xb.x*w1[4] + xb.y*w1[5] + xb.z*w1[6] + xb.w*w1[7];
        }
    }
    float* base = qkv + (size_t)mat * HN*MM*DD;
    const int h0 = c0 >> 7, d0 = c0 & 127;
    const int h1 = c1 >> 7, d1 = c1 & 127;
#pragma unroll
    for (int m = 0; m < MM; ++m) {
        atomicAdd(&base[(h0*MM + m)*DD + d0], a0[m]);
        atomicAdd(&base[(h1*MM + m)*DD + d1], a1[m]);
    }
}

// ---------------- Kernel 2: flash-decode partials ----------------
// grid = (NCH=32, HN=32) = 1024 blocks = exactly 4/CU (LDS 38.9KB).
// 64-row tiles, K-only LDS, V direct from global, 2 barriers/tile.
// 4 waves; wave wv owns m rows 4wv..4wv+3; lane = p in scores.
__global__ __launch_bounds__(256, 2) void attn_partial6(
    const float* __restrict__ cacheK, const float* __restrict__ cacheV,
    const float* __restrict__ qkv, float* __restrict__ pmu,
    float* __restrict__ ps, float* __restrict__ pacc)
{
    __shared__ float Ks[TP][DD + 4];   // 33.8 KB, K tile only
    __shared__ float Wl[TP][20];       // 5.1 KB, weights [p][m-quad per wave]

    const int chunk = blockIdx.x;
    const int h     = blockIdx.y;
    const int t     = threadIdx.x;
    const int lane  = t & 63;
    const int wv    = __builtin_amdgcn_readfirstlane((int)(threadIdx.x >> 6));
    const int srow  = t >> 5;          // staging row base 0..7
    const int sg    = t & 31;          // staging granule (16B)
    const int psi   = lane >> 4;       // PV p-phase 0..3
    const int g     = lane & 15;       // PV d-slice (8 floats)

    const float* k_ws = qkv + HN*MM*DD;
    const float* v_ws = qkv + 2*HN*MM*DD;
    const int start = chunk * CROWS;
    const float* Kbase = cacheK + ((size_t)h*PP + start)*DD;
    const float* Vbase = cacheV + ((size_t)h*PP + start)*DD;
    const float* qb    = qkv + ((size_t)h*MM + 4*wv)*DD;   // wave-uniform Q rows

    const int ntile = 4 + (chunk == NCH - 1 ? 1 : 0);

    float mu0 = -3.0e38f, mu1 = -3.0e38f, mu2 = -3.0e38f, mu3 = -3.0e38f;
    float ss0 = 0.f, ss1 = 0.f, ss2 = 0.f, ss3 = 0.f;
    float acc[4][8];
#pragma unroll
    for (int q = 0; q < 4; ++q)
#pragma unroll
        for (int k = 0; k < 8; ++k) acc[q][k] = 0.f;

    for (int tt = 0; tt < ntile; ++tt) {
        const bool tail  = (tt == 4);          // only chunk 31
        const int  valid = tail ? MM : TP;

        // ---- stage K tile (scores(tt-1) readers all passed B2(tt-1)) ----
        const float* srcK = tail ? k_ws + (size_t)h*MM*DD
                                 : Kbase + (size_t)tt*TP*DD;
#pragma unroll
        for (int rr = 0; rr < 8; ++rr) {
            const int row  = srow + 8*rr;
            const int srcr = tail ? min(row, MM - 1) : row;
            float4 kk = *reinterpret_cast<const float4*>(srcK + (size_t)srcr*DD + sg*4);
            *reinterpret_cast<float4*>(&Ks[row][sg*4]) = kk;
        }
        __syncthreads();                  // B1: K visible (also: PV(tt-1) finished)

        // ---- scores: lane p = lane; K from LDS, Q wave-uniform L1 broadcast ----
        float s0 = 0.f, s1 = 0.f, s2 = 0.f, s3 = 0.f;
#pragma unroll 8
        for (int dq = 0; dq < 32; ++dq) {
            float4 k  = *reinterpret_cast<const float4*>(&Ks[lane][dq*4]);
            const float* qp = qb + dq*4;
            float4 q0 = *reinterpret_cast<const float4*>(qp);
            float4 q1 = *reinterpret_cast<const float4*>(qp + DD);
            float4 q2 = *reinterpret_cast<const float4*>(qp + 2*DD);
            float4 q3 = *reinterpret_cast<const float4*>(qp + 3*DD);
            s0 += k.x*q0.x + k.y*q0.y + k.z*q0.z + k.w*q0.w;
            s1 += k.x*q1.x + k.y*q1.y + k.z*q1.z + k.w*q1.w;
            s2 += k.x*q2.x + k.y*q2.y + k.z*q2.z + k.w*q2.w;
            s3 += k.x*q3.x + k.y*q3.y + k.z*q3.z + k.w*q3.w;
        }
        if (lane >= valid) { s0 = s1 = s2 = s3 = -3.0e38f; }

        // ---- softmax: registers + 64-lane all-reduce (DPP/permlane) ----
        float m0 = s0, m1 = s1, m2 = s2, m3 = s3;
#pragma unroll
        for (int off = 1; off < 64; off <<= 1) {
            m0 = fmaxf(m0, __shfl_xor(m0, off));
            m1 = fmaxf(m1, __shfl_xor(m1, off));
            m2 = fmaxf(m2, __shfl_xor(m2, off));
            m3 = fmaxf(m3, __shfl_xor(m3, off));
        }
        const float n0 = fmaxf(mu0, m0), n1 = fmaxf(mu1, m1);
        const float n2 = fmaxf(mu2, m2), n3 = fmaxf(mu3, m3);
        const float r0 = __expf(mu0 - n0), r1 = __expf(mu1 - n1);
        const float r2 = __expf(mu2 - n2), r3 = __expf(mu3 - n3);
        const float w0 = __expf(s0 - n0);   // invalid p -> exp(-huge) = 0
        const float w1 = __expf(s1 - n1);
        const float w2 = __expf(s2 - n2);
        const float w3 = __expf(s3 - n3);
        float t0s = w0, t1s = w1, t2s = w2, t3s = w3;
#pragma unroll
        for (int off = 1; off < 64; off <<= 1) {
            t0s += __shfl_xor(t0s, off);
            t1s += __shfl_xor(t1s, off);
            t2s += __shfl_xor(t2s, off);
            t3s += __shfl_xor(t3s, off);
        }
        ss0 = ss0*r0 + t0s; ss1 = ss1*r1 + t1s;
        ss2 = ss2*r2 + t2s; ss3 = ss3*r3 + t3s;
        mu0 = n0; mu1 = n1; mu2 = n2; mu3 = n3;
        *reinterpret_cast<float4*>(&Wl[lane][4*wv]) = make_float4(w0, w1, w2, w3);

        __syncthreads();                  // B2: Wl visible; K reads done

        // ---- PV: V straight from global (coalesced 4x512B/wave), Wl from LDS ----
#pragma unroll
        for (int k = 0; k < 8; ++k) {
            acc[0][k] *= r0; acc[1][k] *= r1; acc[2][k] *= r2; acc[3][k] *= r3;
        }
        const float* srcV = tail ? v_ws + (size_t)h*MM*DD
                                 : Vbase + (size_t)tt*TP*DD;
#pragma unroll 4
        for (int i = 0; i < 16; ++i) {
            const int p    = psi + 4*i;
            const int srcr = tail ? min(p, MM - 1) : p;
            const float* vp = srcV + (size_t)srcr*DD + g*8;
            float4 wq = *reinterpret_cast<const float4*>(&Wl[p][4*wv]);
            float4 v0 = *reinterpret_cast<const float4*>(vp);
            float4 v1 = *reinterpret_cast<const float4*>(vp + 4);
            acc[0][0] += wq.x*v0.x; acc[0][1] += wq.x*v0.y; acc[0][2] += wq.x*v0.z; acc[0][3] += wq.x*v0.w;
            acc[0][4] += wq.x*v1.x; acc[0][5] += wq.x*v1.y; acc[0][6] += wq.x*v1.z; acc[0][7] += wq.x*v1.w;
            acc[1][0] += wq.y*v0.x; acc[1][1] += wq.y*v0.y; acc[1][2] += wq.y*v0.z; acc[1][3] += wq.y*v0.w;
            acc[1][4] += wq.y*v1.x; acc[1][5] += wq.y*v1.y; acc[1][6] += wq.y*v1.z; acc[1][7] += wq.y*v1.w;
            acc[2][0] += wq.z*v0.x; acc[2][1] += wq.z*v0.y; acc[2][2] += wq.z*v0.z; acc[2][3] += wq.z*v0.w;
            acc[2][4] += wq.z*v1.x; acc[2][5] += wq.z*v1.y; acc[2][6] += wq.z*v1.z; acc[2][7] += wq.z*v1.w;
            acc[3][0] += wq.w*v0.x; acc[3][1] += wq.w*v0.y; acc[3][2] += wq.w*v0.z; acc[3][3] += wq.w*v0.w;
            acc[3][4] += wq.w*v1.x; acc[3][5] += wq.w*v1.y; acc[3][6] += wq.w*v1.z; acc[3][7] += wq.w*v1.w;
        }
    }

    // ---- epilogue: reduce psi-partials via shuffles, write partials ----
#pragma unroll
    for (int q = 0; q < 4; ++q)
#pragma unroll
        for (int k = 0; k < 8; ++k) {
            float v = acc[q][k];
            v += __shfl_xor(v, 16);
            v += __shfl_xor(v, 32);
            acc[q][k] = v;
        }
    if (lane < 16) {                      // psi == 0 lanes hold full sums
        float* pa = pacc + ((size_t)(h*NCH + chunk)*MM + 4*wv)*DD;
#pragma unroll
        for (int q = 0; q < 4; ++q) {
            *reinterpret_cast<float4*>(pa + q*DD + g*8) =
                make_float4(acc[q][0], acc[q][1], acc[q][2], acc[q][3]);
            *reinterpret_cast<float4*>(pa + q*DD + g*8 + 4) =
                make_float4(acc[q][4], acc[q][5], acc[q][6], acc[q][7]);
        }
    }
    if (lane == 0) {
        const int o = (h*NCH + chunk)*MM + 4*wv;
        pmu[o + 0] = mu0; pmu[o + 1] = mu1; pmu[o + 2] = mu2; pmu[o + 3] = mu3;
        ps [o + 0] = ss0; ps [o + 1] = ss1; ps [o + 2] = ss2; ps [o + 3] = ss3;
    }
}

// ---------------- Kernel 3: combine partials ----------------
__global__ __launch_bounds__(128) void combine_kernel(
    const float* __restrict__ pmu, const float* __restrict__ ps,
    const float* __restrict__ pacc, float* __restrict__ out)
{
    const int b = blockIdx.x;          // h*16 + m
    const int h = b >> 4, m = b & 15;
    const int d = threadIdx.x;
    float gm = -3.0e38f;
#pragma unroll 8
    for (int c = 0; c < NCH; ++c)
        gm = fmaxf(gm, pmu[(h*NCH + c)*MM + m]);
    float stot = 0.f, a = 0.f;
#pragma unroll 8
    for (int c = 0; c < NCH; ++c) {
        const float f = __expf(pmu[(h*NCH + c)*MM + m] - gm);
        stot += ps[(h*NCH + c)*MM + m] * f;
        a += pacc[((size_t)(h*NCH + c)*MM + m)*DD + d] * f;
    }
    out[m*NN + h*DD + d] = a / stot;
}

extern "C" void kernel_launch(void* const* d_in, const int* in_sizes, int n_in,
                              void* d_out, int out_size, void* d_ws, size_t ws_size,
                              hipStream_t stream) {
    const float* X  = (const float*)d_in[0];
    const float* Wq = (const float*)d_in[1];
    const float* Wk = (const float*)d_in[2];
    const float* Wv = (const float*)d_in[3];
    const float* cK = (const float*)d_in[4];
    const float* cV = (const float*)d_in[5];
    float* out = (float*)d_out;

    float* ws     = (float*)d_ws;
    float* qkv    = ws;
    float* pmu_p  = ws + 3*HN*MM*DD;
    float* ps_p   = pmu_p + HN*NCH*MM;
    float* pacc_p = ps_p + HN*NCH*MM;

    hipMemsetAsync(qkv, 0, (size_t)3*HN*MM*DD*sizeof(float), stream);
    qkv_kernel<<<768, 256, 0, stream>>>(X, Wq, Wk, Wv, qkv);
    attn_partial6<<<dim3(NCH, HN), 256, 0, stream>>>(cK, cV, qkv, pmu_p, ps_p, pacc_p);
    combine_kernel<<<HN*MM, 128, 0, stream>>>(pmu_p, ps_p, pacc_p, out);
}